// Round 3
// baseline (223.193 us; speedup 1.0000x reference)
//
#include <hip/hip_runtime.h>
#include <cstdint>

#define N_ 4
#define L_ 8192
#define S_ 8192
#define H_ 8
#define D_ 64
#define E_ 64
#define HD_ 512       // H_*D_ row stride in floats
#define EPS_ 1e-6f
#define RS_ 68        // padded LDS row stride (floats) for K tile
#define TS_ 32        // s-rows per tile
#define TPB_ 4        // tiles per block (p1)

__device__ __forceinline__ float elu1(float x) {
  return x > 0.0f ? x + 1.0f : __expf(x);
}

__device__ __forceinline__ void gl_lds_16B(const void* g, void* l) {
  __builtin_amdgcn_global_load_lds(
      (const __attribute__((address_space(1))) unsigned int*)g,
      (__attribute__((address_space(3))) unsigned int*)l, 16, 0, 0);
}

// ---------------- zero init for KV/Ksum accumulators ----------------
__global__ void zero_ws_kernel(float4* p, int n4) {
  int i = blockIdx.x * blockDim.x + threadIdx.x;
  if (i < n4) p[i] = make_float4(0.f, 0.f, 0.f, 0.f);
}

// ---------------- phase 1: KV[d][e] = sum_s fK[s][d] * V[s][e]; Ksum[d] -----
// grid (64, H, N), block 512 (8 waves). Block covers 128 s-rows (4 tiles of 32).
// Wave w owns d-slice [8w, 8w+8). Lane (sg=lane>>4, eg=lane&15): s-split 4-way,
// 4 e-columns per lane. acc[8][4]; shfl butterfly collapses sg at end.
__global__ __launch_bounds__(512, 7) void p1_kv(const float* __restrict__ keys,
                                                const float* __restrict__ values,
                                                float* __restrict__ kvg,
                                                float* __restrict__ ksg) {
  const int chunk = blockIdx.x, h = blockIdx.y, n = blockIdx.z;
  const int tid = threadIdx.x;
  const int w = tid >> 6, lane = tid & 63;
  const int sg = lane >> 4, eg = lane & 15;
  __shared__ float fk_lds[TS_ * RS_];   // 8704 B
  __shared__ float v_lds[TS_ * 64];     // 8192 B, unpadded (gl_lds dest)

  const int srow = tid >> 4;            // 0..31
  const int scol = (tid & 15) * 4;

  const float* Kb = keys   + (size_t)n * S_ * HD_ + h * D_;
  const float* Vb = values + (size_t)n * S_ * HD_ + h * D_;

  float acc[8][4];
  #pragma unroll
  for (int i = 0; i < 8; ++i)
    #pragma unroll
    for (int j = 0; j < 4; ++j) acc[i][j] = 0.0f;
  float4 kss = make_float4(0.f, 0.f, 0.f, 0.f);

  const int dbase = w * 8;
  // per-lane source pieces for the V direct-to-LDS load
  const int vrow_off = w * 4 + (lane >> 4);     // row within tile
  const int vcol_off = (lane & 15) * 4;         // float col

  #pragma unroll 1
  for (int t = 0; t < TPB_; ++t) {
    const int s0 = chunk * (TS_ * TPB_) + t * TS_;
    // ---- V: one async global->LDS 16B per wave (1 KiB = rows 4w..4w+3) ----
    gl_lds_16B(Vb + (size_t)(s0 + vrow_off) * HD_ + vcol_off,
               &v_lds[w * 4 * 64]);
    // ---- K: 1 float4 per thread, elu, stage to padded LDS ----
    {
      float4 k4 = *(const float4*)(Kb + (size_t)(s0 + srow) * HD_ + scol);
      float4 f;
      f.x = elu1(k4.x); f.y = elu1(k4.y); f.z = elu1(k4.z); f.w = elu1(k4.w);
      kss.x += f.x; kss.y += f.y; kss.z += f.z; kss.w += f.w;
      *(float4*)&fk_lds[srow * RS_ + scol] = f;
    }
    __syncthreads();   // drains gl_lds (vmcnt) + ds_writes (lgkmcnt)
    // ---- compute: 8 row-quads; lane handles row 4*g4+sg ----
    #pragma unroll
    for (int g4 = 0; g4 < 8; ++g4) {
      const int s = g4 * 4 + sg;
      float4 vv = *(const float4*)&v_lds[s * 64 + eg * 4];
      const float* fr = &fk_lds[s * RS_ + dbase];
      float4 k0 = *(const float4*)(fr + 0);
      float4 k1 = *(const float4*)(fr + 4);
      #define ACCROW(di, kc)                          \
        acc[di][0] = fmaf(kc, vv.x, acc[di][0]);      \
        acc[di][1] = fmaf(kc, vv.y, acc[di][1]);      \
        acc[di][2] = fmaf(kc, vv.z, acc[di][2]);      \
        acc[di][3] = fmaf(kc, vv.w, acc[di][3]);
      ACCROW(0, k0.x) ACCROW(1, k0.y) ACCROW(2, k0.z) ACCROW(3, k0.w)
      ACCROW(4, k1.x) ACCROW(5, k1.y) ACCROW(6, k1.z) ACCROW(7, k1.w)
      #undef ACCROW
    }
    __syncthreads();   // all reads done before next tile's staging
  }

  // ---- butterfly-reduce the 4-way s split ----
  #pragma unroll
  for (int i = 0; i < 8; ++i)
    #pragma unroll
    for (int j = 0; j < 4; ++j) {
      float v = acc[i][j];
      v += __shfl_xor(v, 16, 64);
      v += __shfl_xor(v, 32, 64);
      acc[i][j] = v;
    }

  // ---- commit wave's 8x64 slice via global atomics (lanes sg==0) ----
  const size_t kvoff = (size_t)(n * H_ + h) * (D_ * E_);
  if (sg == 0) {
    #pragma unroll
    for (int i = 0; i < 8; ++i)
      #pragma unroll
      for (int j = 0; j < 4; ++j)
        atomicAdd(&kvg[kvoff + (size_t)(dbase + i) * E_ + eg * 4 + j], acc[i][j]);
  }

  // ---- Ksum block-reduce (reuse v_lds; last barrier already passed) ----
  *(float4*)&v_lds[srow * 64 + scol] = kss;
  __syncthreads();
  if (tid < 64) {
    float s = 0.f;
    #pragma unroll
    for (int r = 0; r < 32; ++r) s += v_lds[r * 64 + tid];
    atomicAdd(&ksg[(size_t)(n * H_ + h) * D_ + tid], s);
  }
}

// ---------------- phase 2: out[l][e] = (fQ[l].KV[:,e]) / (fQ[l].Ksum + eps) ---
// grid (L/64, H, N), block 256 (4 waves), wave handles 16 rows.
// Lane (dg=lane>>4, eg=lane&15): d-reduction split 4-way, 4 e-columns per lane.
__global__ __launch_bounds__(256, 4) void p2_out(const float* __restrict__ queries,
                                                 const float* __restrict__ kvg,
                                                 const float* __restrict__ ksg,
                                                 float* __restrict__ out) {
  const int lt = blockIdx.x, h = blockIdx.y, n = blockIdx.z;
  const int tid = threadIdx.x;
  const int wave = tid >> 6, lane = tid & 63;
  const int dg = lane >> 4, eg = lane & 15;
  __shared__ float q_lds[64 * RS_];

  // KV sub-block into registers: kv[di][ej] = KV[16dg+di][4eg+ej]
  const float* kvb = kvg + (size_t)(n * H_ + h) * (D_ * E_);
  float kv[16][4];
  #pragma unroll
  for (int i = 0; i < 16; ++i) {
    float4 t4 = *(const float4*)&kvb[(size_t)(dg * 16 + i) * E_ + eg * 4];
    kv[i][0] = t4.x; kv[i][1] = t4.y; kv[i][2] = t4.z; kv[i][3] = t4.w;
  }
  float ks[16];
  const float* ksb = ksg + (size_t)(n * H_ + h) * D_ + dg * 16;
  #pragma unroll
  for (int i = 0; i < 16; ++i) ks[i] = ksb[i];

  // stage fQ tile [64][64] (elu applied), coalesced float4
  const float* qb = queries + ((size_t)(n * L_ + lt * 64) * H_ + h) * D_;
  {
    const int srow = tid >> 4, scol = (tid & 15) * 4;
    #pragma unroll
    for (int p = 0; p < 4; ++p) {
      const int r = p * 16 + srow;
      float4 q4 = *(const float4*)(qb + (size_t)r * HD_ + scol);
      float4 f;
      f.x = elu1(q4.x); f.y = elu1(q4.y); f.z = elu1(q4.z); f.w = elu1(q4.w);
      *(float4*)&q_lds[r * RS_ + scol] = f;
    }
  }
  __syncthreads();

  // denominator: lane (dg,eg) -> row wave*16+eg, d-slice dg; butterfly gives
  // every lane den[row wave*16+eg]; keep zden = rcp in-register, no LDS.
  float zden;
  {
    const int r = wave * 16 + eg;
    const float* qr = &q_lds[r * RS_ + dg * 16];
    float4 a = *(const float4*)(qr + 0);
    float4 b = *(const float4*)(qr + 4);
    float4 c = *(const float4*)(qr + 8);
    float4 d = *(const float4*)(qr + 12);
    float s0 = fmaf(a.x, ks[0],  fmaf(a.y, ks[1],  fmaf(a.z, ks[2],  a.w * ks[3])));
    float s1 = fmaf(b.x, ks[4],  fmaf(b.y, ks[5],  fmaf(b.z, ks[6],  b.w * ks[7])));
    float s2 = fmaf(c.x, ks[8],  fmaf(c.y, ks[9],  fmaf(c.z, ks[10], c.w * ks[11])));
    float s3 = fmaf(d.x, ks[12], fmaf(d.y, ks[13], fmaf(d.z, ks[14], d.w * ks[15])));
    float s = (s0 + s1) + (s2 + s3);
    s += __shfl_xor(s, 16, 64);
    s += __shfl_xor(s, 32, 64);
#if __has_builtin(__builtin_amdgcn_rcpf)
    zden = __builtin_amdgcn_rcpf(s + EPS_);
#else
    zden = 1.0f / (s + EPS_);
#endif
  }

  // main loop: 16 rows per wave; 4 broadcast b128 reads feed 64 FMAs per row
  float* ob = out + ((size_t)(n * L_ + lt * 64) * H_ + h) * E_;
  #pragma unroll 2
  for (int rr = 0; rr < 16; ++rr) {
    const int r = wave * 16 + rr;
    const float z = __shfl(zden, rr, 16);   // from lane (dg, rr): row wave*16+rr
    const float* qr = &q_lds[r * RS_ + dg * 16];
    float4 q0 = *(const float4*)(qr + 0);
    float4 q1 = *(const float4*)(qr + 4);
    float4 q2 = *(const float4*)(qr + 8);
    float4 q3 = *(const float4*)(qr + 12);
    float a0 = 0.f, a1 = 0.f, a2 = 0.f, a3 = 0.f;
    #define P2ACC(qc, i)                      \
      a0 = fmaf(qc, kv[i][0], a0);            \
      a1 = fmaf(qc, kv[i][1], a1);            \
      a2 = fmaf(qc, kv[i][2], a2);            \
      a3 = fmaf(qc, kv[i][3], a3);
    P2ACC(q0.x, 0)  P2ACC(q0.y, 1)  P2ACC(q0.z, 2)  P2ACC(q0.w, 3)
    P2ACC(q1.x, 4)  P2ACC(q1.y, 5)  P2ACC(q1.z, 6)  P2ACC(q1.w, 7)
    P2ACC(q2.x, 8)  P2ACC(q2.y, 9)  P2ACC(q2.z, 10) P2ACC(q2.w, 11)
    P2ACC(q3.x, 12) P2ACC(q3.y, 13) P2ACC(q3.z, 14) P2ACC(q3.w, 15)
    #undef P2ACC
    a0 += __shfl_xor(a0, 16, 64); a0 += __shfl_xor(a0, 32, 64);
    a1 += __shfl_xor(a1, 16, 64); a1 += __shfl_xor(a1, 32, 64);
    a2 += __shfl_xor(a2, 16, 64); a2 += __shfl_xor(a2, 32, 64);
    a3 += __shfl_xor(a3, 16, 64); a3 += __shfl_xor(a3, 32, 64);
    if (dg == 0) {
      float4 o;
      o.x = a0 * z; o.y = a1 * z; o.z = a2 * z; o.w = a3 * z;
      *(float4*)(ob + (size_t)r * (H_ * E_) + eg * 4) = o;
    }
  }
}

extern "C" void kernel_launch(void* const* d_in, const int* in_sizes, int n_in,
                              void* d_out, int out_size, void* d_ws, size_t ws_size,
                              hipStream_t stream) {
  const float* q = (const float*)d_in[0];
  const float* k = (const float*)d_in[1];
  const float* v = (const float*)d_in[2];
  float* outp = (float*)d_out;
  float* kvg = (float*)d_ws;                         // N*H*D*E floats
  float* ksg = kvg + (size_t)N_ * H_ * D_ * E_;      // N*H*D floats

  const int ztot = N_ * H_ * (D_ * E_ + D_);
  const int zn4 = ztot / 4;
  hipLaunchKernelGGL(zero_ws_kernel, dim3((zn4 + 255) / 256), dim3(256), 0, stream,
                     (float4*)kvg, zn4);
  // S / (TS*TPB) = 8192 / 128 = 64 chunks
  hipLaunchKernelGGL(p1_kv, dim3(64, H_, N_), dim3(512), 0, stream, k, v, kvg, ksg);
  hipLaunchKernelGGL(p2_out, dim3(L_ / 64, H_, N_), dim3(256), 0, stream, q, kvg, ksg, outp);
}

// Round 4
// 181.040 us; speedup vs baseline: 1.2328x; 1.2328x over previous
//
#include <hip/hip_runtime.h>
#include <cstdint>

#define N_ 4
#define L_ 8192
#define S_ 8192
#define H_ 8
#define D_ 64
#define E_ 64
#define HD_ 512       // H_*D_ row stride in floats
#define NH_ 32        // N_*H_
#define EPS_ 1e-6f
#define RS_ 68        // padded LDS row stride (floats) for K/Q tiles
#define TS_ 32        // s-rows per tile (p1)

__device__ __forceinline__ float elu1(float x) {
  return x > 0.0f ? x + 1.0f : __expf(x);
}

__device__ __forceinline__ void gl_lds_16B(const void* g, void* l) {
  __builtin_amdgcn_global_load_lds(
      (const __attribute__((address_space(1))) unsigned int*)g,
      (__attribute__((address_space(3))) unsigned int*)l, 16, 0, 0);
}

// ---------------- phase 1: partial KV/Ksum per block (NO atomics) -----------
// grid (C, H, N), block 512 (8 waves). Block covers tiles*32 s-rows.
// Wave w owns d-slice [8w, 8w+8). Lane (sg=lane>>4, eg=lane&15): s-split 4-way,
// 4 e-columns per lane. acc[8][4]; shfl butterfly collapses sg at end.
// Pipeline: V[t+1] via global_load_lds (double-buffered) + K[t+1] via regs are
// issued before compute(t); the end-of-tile barrier drains them under compute.
__global__ __launch_bounds__(512, 8) void p1_kv(const float* __restrict__ keys,
                                                const float* __restrict__ values,
                                                float* __restrict__ pkv,
                                                float* __restrict__ pks,
                                                int tiles) {
  const int chunk = blockIdx.x, h = blockIdx.y, n = blockIdx.z;
  const int tid = threadIdx.x;
  const int w = tid >> 6, lane = tid & 63;
  const int sg = lane >> 4, eg = lane & 15;
  __shared__ float fk_lds[TS_ * RS_];       // 8704 B (padded, reg-staged K)
  __shared__ float v_lds[2 * TS_ * 64];     // 16 KiB, double-buffered gl_lds dest

  const int srow = tid >> 4;                // 0..31
  const int scol = (tid & 15) * 4;

  const float* Kb = keys   + (size_t)n * S_ * HD_ + h * D_;
  const float* Vb = values + (size_t)n * S_ * HD_ + h * D_;

  float acc[8][4];
  #pragma unroll
  for (int i = 0; i < 8; ++i)
    #pragma unroll
    for (int j = 0; j < 4; ++j) acc[i][j] = 0.0f;
  float4 kss = make_float4(0.f, 0.f, 0.f, 0.f);

  const int dbase = w * 8;
  const int vrow = w * 4 + (lane >> 4);     // V source row within tile
  const int vcol = (lane & 15) * 4;
  const int sbase = chunk * tiles * TS_;

  // prologue: issue K[0] (regs) + V[0] (gl_lds -> buffer 0)
  float4 kreg = *(const float4*)(Kb + (size_t)(sbase + srow) * HD_ + scol);
  gl_lds_16B(Vb + (size_t)(sbase + vrow) * HD_ + vcol, &v_lds[w * 256]);

  #pragma unroll 1
  for (int t = 0; t < tiles; ++t) {
    // elu + stage K tile t from regs
    float4 f;
    f.x = elu1(kreg.x); f.y = elu1(kreg.y); f.z = elu1(kreg.z); f.w = elu1(kreg.w);
    kss.x += f.x; kss.y += f.y; kss.z += f.z; kss.w += f.w;
    *(float4*)&fk_lds[srow * RS_ + scol] = f;
    __syncthreads();   // fk writes visible; V[t] arrived (issued last iter/prologue)

    const float* vb = &v_lds[(t & 1) * (TS_ * 64)];
    if (t + 1 < tiles) {  // issue next tile's loads; drained by the barrier below
      const int s1 = sbase + (t + 1) * TS_;
      kreg = *(const float4*)(Kb + (size_t)(s1 + srow) * HD_ + scol);
      gl_lds_16B(Vb + (size_t)(s1 + vrow) * HD_ + vcol,
                 &v_lds[((t + 1) & 1) * (TS_ * 64) + w * 256]);
    }

    // compute tile t: 8 row-quads; lane handles row 4*g4+sg
    #pragma unroll
    for (int g4 = 0; g4 < 8; ++g4) {
      const int s = g4 * 4 + sg;
      float4 vv = *(const float4*)&vb[s * 64 + eg * 4];
      const float* fr = &fk_lds[s * RS_ + dbase];
      float4 k0 = *(const float4*)(fr + 0);
      float4 k1 = *(const float4*)(fr + 4);
      #define ACCROW(di, kc)                          \
        acc[di][0] = fmaf(kc, vv.x, acc[di][0]);      \
        acc[di][1] = fmaf(kc, vv.y, acc[di][1]);      \
        acc[di][2] = fmaf(kc, vv.z, acc[di][2]);      \
        acc[di][3] = fmaf(kc, vv.w, acc[di][3]);
      ACCROW(0, k0.x) ACCROW(1, k0.y) ACCROW(2, k0.z) ACCROW(3, k0.w)
      ACCROW(4, k1.x) ACCROW(5, k1.y) ACCROW(6, k1.z) ACCROW(7, k1.w)
      #undef ACCROW
    }
    __syncthreads();   // reads done; also drains K[t+1]/V[t+1] (covered by compute)
  }

  // butterfly-reduce the 4-way s split
  #pragma unroll
  for (int i = 0; i < 8; ++i)
    #pragma unroll
    for (int j = 0; j < 4; ++j) {
      float v = acc[i][j];
      v += __shfl_xor(v, 16, 64);
      v += __shfl_xor(v, 32, 64);
      acc[i][j] = v;
    }

  // plain coalesced stores of the block's partial 64x64 tile
  float* pkvb = pkv + ((size_t)chunk * NH_ + (size_t)(n * H_ + h)) * (D_ * E_);
  if (sg == 0) {
    #pragma unroll
    for (int i = 0; i < 8; ++i) {
      float4 o = make_float4(acc[i][0], acc[i][1], acc[i][2], acc[i][3]);
      *(float4*)&pkvb[(dbase + i) * E_ + eg * 4] = o;
    }
  }

  // partial Ksum: block-reduce in LDS (v_lds reusable after final barrier)
  *(float4*)&v_lds[srow * 64 + scol] = kss;
  __syncthreads();
  if (tid < 64) {
    float s = 0.f;
    #pragma unroll
    for (int r = 0; r < 32; ++r) s += v_lds[r * 64 + tid];
    pks[((size_t)chunk * NH_ + (size_t)(n * H_ + h)) * D_ + tid] = s;
  }
}

// ---------------- reduce partials -> KV, Ksum ----------------
// grid (17, NH), block 256. bx<16: KV elements; bx==16: Ksum.
__global__ __launch_bounds__(256) void reduce_kv(const float* __restrict__ pkv,
                                                 const float* __restrict__ pks,
                                                 float* __restrict__ kvg,
                                                 float* __restrict__ ksg, int C) {
  const int nh = blockIdx.y;
  if (blockIdx.x < 16) {
    const int idx = blockIdx.x * 256 + threadIdx.x;
    float s = 0.f;
    #pragma unroll 1
    for (int c = 0; c < C; ++c)
      s += pkv[((size_t)c * NH_ + nh) * (D_ * E_) + idx];
    kvg[(size_t)nh * (D_ * E_) + idx] = s;
  } else if (threadIdx.x < 64) {
    float s = 0.f;
    #pragma unroll 1
    for (int c = 0; c < C; ++c)
      s += pks[((size_t)c * NH_ + nh) * D_ + threadIdx.x];
    ksg[(size_t)nh * D_ + threadIdx.x] = s;
  }
}

// ---------------- phase 2: out[l][e] = (fQ[l].KV[:,e]) / (fQ[l].Ksum + eps) ---
// grid (L/64, H, N), block 256 (4 waves), wave handles 16 rows.
// Lane (dg=lane>>4, eg=lane&15). Denominator fused into the main loop; output
// stores widened to full-wave float4 every 4 rows (dg-selected pending value).
__global__ __launch_bounds__(256, 4) void p2_out(const float* __restrict__ queries,
                                                 const float* __restrict__ kvg,
                                                 const float* __restrict__ ksg,
                                                 float* __restrict__ out) {
  const int lt = blockIdx.x, h = blockIdx.y, n = blockIdx.z;
  const int tid = threadIdx.x;
  const int wave = tid >> 6, lane = tid & 63;
  const int dg = lane >> 4, eg = lane & 15;
  __shared__ float q_lds[64 * RS_];

  // KV sub-block: kv[di][ej] = KV[16dg+di][4eg+ej]
  const float* kvb = kvg + (size_t)(n * H_ + h) * (D_ * E_);
  float kv[16][4];
  #pragma unroll
  for (int i = 0; i < 16; ++i) {
    float4 t4 = *(const float4*)&kvb[(size_t)(dg * 16 + i) * E_ + eg * 4];
    kv[i][0] = t4.x; kv[i][1] = t4.y; kv[i][2] = t4.z; kv[i][3] = t4.w;
  }
  float ks[16];
  const float* ksb = ksg + (size_t)(n * H_ + h) * D_ + dg * 16;
  #pragma unroll
  for (int i = 0; i < 16; ++i) ks[i] = ksb[i];

  // stage fQ tile [64][64] (elu applied), coalesced float4
  const float* qb = queries + ((size_t)(n * L_ + lt * 64) * H_ + h) * D_;
  {
    const int srow = tid >> 4, scol = (tid & 15) * 4;
    #pragma unroll
    for (int p = 0; p < 4; ++p) {
      const int r = p * 16 + srow;
      float4 q4 = *(const float4*)(qb + (size_t)r * HD_ + scol);
      float4 f;
      f.x = elu1(q4.x); f.y = elu1(q4.y); f.z = elu1(q4.z); f.w = elu1(q4.w);
      *(float4*)&q_lds[r * RS_ + scol] = f;
    }
  }
  __syncthreads();

  float* ob = out + ((size_t)(n * L_ + lt * 64) * H_ + h) * E_;
  float4 o4 = make_float4(0.f, 0.f, 0.f, 0.f);
  #pragma unroll 4
  for (int rr = 0; rr < 16; ++rr) {
    const int r = wave * 16 + rr;
    const float* qr = &q_lds[r * RS_ + dg * 16];
    float4 q0 = *(const float4*)(qr + 0);
    float4 q1 = *(const float4*)(qr + 4);
    float4 q2 = *(const float4*)(qr + 8);
    float4 q3 = *(const float4*)(qr + 12);
    float a0 = 0.f, a1 = 0.f, a2 = 0.f, a3 = 0.f, dn = 0.f;
    #define P2ACC(qc, i)                      \
      a0 = fmaf(qc, kv[i][0], a0);            \
      a1 = fmaf(qc, kv[i][1], a1);            \
      a2 = fmaf(qc, kv[i][2], a2);            \
      a3 = fmaf(qc, kv[i][3], a3);            \
      dn = fmaf(qc, ks[i], dn);
    P2ACC(q0.x, 0)  P2ACC(q0.y, 1)  P2ACC(q0.z, 2)  P2ACC(q0.w, 3)
    P2ACC(q1.x, 4)  P2ACC(q1.y, 5)  P2ACC(q1.z, 6)  P2ACC(q1.w, 7)
    P2ACC(q2.x, 8)  P2ACC(q2.y, 9)  P2ACC(q2.z, 10) P2ACC(q2.w, 11)
    P2ACC(q3.x, 12) P2ACC(q3.y, 13) P2ACC(q3.z, 14) P2ACC(q3.w, 15)
    #undef P2ACC
    a0 += __shfl_xor(a0, 16, 64); a0 += __shfl_xor(a0, 32, 64);
    a1 += __shfl_xor(a1, 16, 64); a1 += __shfl_xor(a1, 32, 64);
    a2 += __shfl_xor(a2, 16, 64); a2 += __shfl_xor(a2, 32, 64);
    a3 += __shfl_xor(a3, 16, 64); a3 += __shfl_xor(a3, 32, 64);
    dn += __shfl_xor(dn, 16, 64); dn += __shfl_xor(dn, 32, 64);
#if __has_builtin(__builtin_amdgcn_rcpf)
    float z = __builtin_amdgcn_rcpf(dn + EPS_);
#else
    float z = 1.0f / (dn + EPS_);
#endif
    if (dg == (rr & 3)) { o4.x = a0 * z; o4.y = a1 * z; o4.z = a2 * z; o4.w = a3 * z; }
    if ((rr & 3) == 3) {   // full-wave 1 KiB store: lane (dg,eg) -> row base+dg
      const int rb = wave * 16 + (rr & ~3) + dg;
      *(float4*)(ob + (size_t)rb * (H_ * E_) + eg * 4) = o4;
    }
  }
}

extern "C" void kernel_launch(void* const* d_in, const int* in_sizes, int n_in,
                              void* d_out, int out_size, void* d_ws, size_t ws_size,
                              hipStream_t stream) {
  const float* q = (const float*)d_in[0];
  const float* k = (const float*)d_in[1];
  const float* v = (const float*)d_in[2];
  float* outp = (float*)d_out;

  float* kvg = (float*)d_ws;                         // NH * 4096
  float* ksg = kvg + (size_t)NH_ * D_ * E_;          // NH * 64
  float* pkv = ksg + (size_t)NH_ * D_;               // C * NH * 4096
  // pick partial count C by available workspace (prefer 32)
  int C = 32;
  while (C > 1) {
    size_t need = ((size_t)NH_ * D_ * E_ + (size_t)NH_ * D_ +
                   (size_t)C * NH_ * (D_ * E_ + D_)) * sizeof(float);
    if (need <= ws_size) break;
    C >>= 1;
  }
  float* pks = pkv + (size_t)C * NH_ * (D_ * E_);
  const int tiles = S_ / (C * TS_);

  hipLaunchKernelGGL(p1_kv, dim3(C, H_, N_), dim3(512), 0, stream, k, v, pkv, pks, tiles);
  hipLaunchKernelGGL(reduce_kv, dim3(17, NH_), dim3(256), 0, stream, pkv, pks, kvg, ksg, C);
  hipLaunchKernelGGL(p2_out, dim3(L_ / 64, H_, N_), dim3(256), 0, stream, q, kvg, ksg, outp);
}

// Round 5
// 144.901 us; speedup vs baseline: 1.5403x; 1.2494x over previous
//
#include <hip/hip_runtime.h>
#include <cstdint>

#define N_ 4
#define L_ 8192
#define S_ 8192
#define H_ 8
#define D_ 64
#define E_ 64
#define HD_ 512       // H_*D_ row stride in floats
#define NH_ 32        // N_*H_
#define EPS_ 1e-6f
#define RS_ 68        // padded LDS row stride (floats) for K/Q tiles
#define TS_ 32        // s-rows per tile (p1)

__device__ __forceinline__ float elu1(float x) {
  return x > 0.0f ? x + 1.0f : __expf(x);
}

__device__ __forceinline__ void gl_lds_16B(const void* g, void* l) {
  __builtin_amdgcn_global_load_lds(
      (const __attribute__((address_space(1))) unsigned int*)g,
      (__attribute__((address_space(3))) unsigned int*)l, 16, 0, 0);
}

// ---------------- phase 1: partial KV/Ksum per block (NO atomics) -----------
// grid (C, H, N), block 512 (8 waves). Block covers tiles*32 s-rows.
// Wave w owns d-slice [8w, 8w+8). Lane (sg=lane>>4, eg=lane&15): s-split 4-way,
// 4 e-columns per lane. acc[8][4] (AGPR-side); butterfly collapses sg at end.
// V[t+1] prefetched via global_load_lds (zero-VGPR) into a double buffer; K is
// loaded at point of use — its latency is covered by 4 independent blocks/CU.
// Register budget: peak live ~56 < 64 (launch_bounds 512,8) -> no scratch.
__global__ __launch_bounds__(512, 8) void p1_kv(const float* __restrict__ keys,
                                                const float* __restrict__ values,
                                                float* __restrict__ pkv,
                                                float* __restrict__ pks,
                                                int tiles) {
  const int chunk = blockIdx.x, h = blockIdx.y, n = blockIdx.z;
  const int tid = threadIdx.x;
  const int w = tid >> 6, lane = tid & 63;
  const int sg = lane >> 4, eg = lane & 15;
  __shared__ float fk_lds[TS_ * RS_];       // 8704 B (padded, reg-staged K)
  __shared__ float v_lds[2 * TS_ * 64];     // 16 KiB, double-buffered gl_lds dest

  const int srow = tid >> 4;                // 0..31 == w*4 + sg (also V src row)
  const int scol = (tid & 15) * 4;          // == eg*4 (also V src col)

  const float* Kb = keys   + (size_t)n * S_ * HD_ + h * D_;
  const float* Vb = values + (size_t)n * S_ * HD_ + h * D_;

  float acc[8][4];
  #pragma unroll
  for (int i = 0; i < 8; ++i)
    #pragma unroll
    for (int j = 0; j < 4; ++j) acc[i][j] = 0.0f;
  float4 kss = make_float4(0.f, 0.f, 0.f, 0.f);

  const int dbase = w * 8;
  const int sbase = chunk * tiles * TS_;

  // prologue: issue V[0] (gl_lds -> buffer 0); source row/col = srow/scol
  gl_lds_16B(Vb + (size_t)(sbase + srow) * HD_ + scol, &v_lds[w * 256]);

  #pragma unroll 1
  for (int t = 0; t < tiles; ++t) {
    // K tile t: load at point of use (no loop-carried prefetch regs)
    {
      float4 k4 = *(const float4*)(Kb + (size_t)(sbase + t * TS_ + srow) * HD_ + scol);
      float4 f;
      f.x = elu1(k4.x); f.y = elu1(k4.y); f.z = elu1(k4.z); f.w = elu1(k4.w);
      kss.x += f.x; kss.y += f.y; kss.z += f.z; kss.w += f.w;
      *(float4*)&fk_lds[srow * RS_ + scol] = f;
    }
    __syncthreads();   // fk writes visible; V[t] landed (issued prev iter/prologue)

    const float* vb = &v_lds[(t & 1) * (TS_ * 64)];
    if (t + 1 < tiles) {  // V[t+1] async -> other buffer; drains at next barrier
      gl_lds_16B(Vb + (size_t)(sbase + (t + 1) * TS_ + srow) * HD_ + scol,
                 &v_lds[((t + 1) & 1) * (TS_ * 64) + w * 256]);
    }

    // compute tile t: 8 row-quads; lane handles row 4*g4+sg
    #pragma unroll
    for (int g4 = 0; g4 < 8; ++g4) {
      const int s = g4 * 4 + sg;
      float4 vv = *(const float4*)&vb[s * 64 + eg * 4];
      const float* fr = &fk_lds[s * RS_ + dbase];
      float4 k0 = *(const float4*)(fr + 0);
      float4 k1 = *(const float4*)(fr + 4);
      #define ACCROW(di, kc)                          \
        acc[di][0] = fmaf(kc, vv.x, acc[di][0]);      \
        acc[di][1] = fmaf(kc, vv.y, acc[di][1]);      \
        acc[di][2] = fmaf(kc, vv.z, acc[di][2]);      \
        acc[di][3] = fmaf(kc, vv.w, acc[di][3]);
      ACCROW(0, k0.x) ACCROW(1, k0.y) ACCROW(2, k0.z) ACCROW(3, k0.w)
      ACCROW(4, k1.x) ACCROW(5, k1.y) ACCROW(6, k1.z) ACCROW(7, k1.w)
      #undef ACCROW
    }
    __syncthreads();   // reads done before fk/v_lds rewrite
  }

  // butterfly-reduce the 4-way s split
  #pragma unroll
  for (int i = 0; i < 8; ++i)
    #pragma unroll
    for (int j = 0; j < 4; ++j) {
      float v = acc[i][j];
      v += __shfl_xor(v, 16, 64);
      v += __shfl_xor(v, 32, 64);
      acc[i][j] = v;
    }

  // plain coalesced stores of the block's partial 64x64 tile
  float* pkvb = pkv + ((size_t)chunk * NH_ + (size_t)(n * H_ + h)) * (D_ * E_);
  if (sg == 0) {
    #pragma unroll
    for (int i = 0; i < 8; ++i) {
      float4 o = make_float4(acc[i][0], acc[i][1], acc[i][2], acc[i][3]);
      *(float4*)&pkvb[(dbase + i) * E_ + eg * 4] = o;
    }
  }

  // partial Ksum: block-reduce in LDS (v_lds reusable after final barrier)
  *(float4*)&v_lds[srow * 64 + scol] = kss;
  __syncthreads();
  if (tid < 64) {
    float s = 0.f;
    #pragma unroll
    for (int r = 0; r < 32; ++r) s += v_lds[r * 64 + tid];
    pks[((size_t)chunk * NH_ + (size_t)(n * H_ + h)) * D_ + tid] = s;
  }
}

// ---------------- reduce partials -> KV, Ksum ----------------
// grid (17, NH), block 256. bx<16: KV elements; bx==16: Ksum.
__global__ __launch_bounds__(256) void reduce_kv(const float* __restrict__ pkv,
                                                 const float* __restrict__ pks,
                                                 float* __restrict__ kvg,
                                                 float* __restrict__ ksg, int C) {
  const int nh = blockIdx.y;
  if (blockIdx.x < 16) {
    const int idx = blockIdx.x * 256 + threadIdx.x;
    float s = 0.f;
    #pragma unroll 1
    for (int c = 0; c < C; ++c)
      s += pkv[((size_t)c * NH_ + nh) * (D_ * E_) + idx];
    kvg[(size_t)nh * (D_ * E_) + idx] = s;
  } else if (threadIdx.x < 64) {
    float s = 0.f;
    #pragma unroll 1
    for (int c = 0; c < C; ++c)
      s += pks[((size_t)c * NH_ + nh) * D_ + threadIdx.x];
    ksg[(size_t)nh * D_ + threadIdx.x] = s;
  }
}

// ---------------- phase 2: out[l][e] = (fQ[l].KV[:,e]) / (fQ[l].Ksum + eps) ---
// grid (L/64, H, N), block 256 (4 waves), wave handles 16 rows.
// Lane (dg=lane>>4, eg=lane&15). Denominator fused into the main loop; output
// stores widened to full-wave float4 every 4 rows (dg-selected pending value).
__global__ __launch_bounds__(256, 4) void p2_out(const float* __restrict__ queries,
                                                 const float* __restrict__ kvg,
                                                 const float* __restrict__ ksg,
                                                 float* __restrict__ out) {
  const int lt = blockIdx.x, h = blockIdx.y, n = blockIdx.z;
  const int tid = threadIdx.x;
  const int wave = tid >> 6, lane = tid & 63;
  const int dg = lane >> 4, eg = lane & 15;
  __shared__ float q_lds[64 * RS_];

  // KV sub-block: kv[di][ej] = KV[16dg+di][4eg+ej]
  const float* kvb = kvg + (size_t)(n * H_ + h) * (D_ * E_);
  float kv[16][4];
  #pragma unroll
  for (int i = 0; i < 16; ++i) {
    float4 t4 = *(const float4*)&kvb[(size_t)(dg * 16 + i) * E_ + eg * 4];
    kv[i][0] = t4.x; kv[i][1] = t4.y; kv[i][2] = t4.z; kv[i][3] = t4.w;
  }
  float ks[16];
  const float* ksb = ksg + (size_t)(n * H_ + h) * D_ + dg * 16;
  #pragma unroll
  for (int i = 0; i < 16; ++i) ks[i] = ksb[i];

  // stage fQ tile [64][64] (elu applied), coalesced float4
  const float* qb = queries + ((size_t)(n * L_ + lt * 64) * H_ + h) * D_;
  {
    const int srow = tid >> 4, scol = (tid & 15) * 4;
    #pragma unroll
    for (int p = 0; p < 4; ++p) {
      const int r = p * 16 + srow;
      float4 q4 = *(const float4*)(qb + (size_t)r * HD_ + scol);
      float4 f;
      f.x = elu1(q4.x); f.y = elu1(q4.y); f.z = elu1(q4.z); f.w = elu1(q4.w);
      *(float4*)&q_lds[r * RS_ + scol] = f;
    }
  }
  __syncthreads();

  float* ob = out + ((size_t)(n * L_ + lt * 64) * H_ + h) * E_;
  float4 o4 = make_float4(0.f, 0.f, 0.f, 0.f);
  #pragma unroll 4
  for (int rr = 0; rr < 16; ++rr) {
    const int r = wave * 16 + rr;
    const float* qr = &q_lds[r * RS_ + dg * 16];
    float4 q0 = *(const float4*)(qr + 0);
    float4 q1 = *(const float4*)(qr + 4);
    float4 q2 = *(const float4*)(qr + 8);
    float4 q3 = *(const float4*)(qr + 12);
    float a0 = 0.f, a1 = 0.f, a2 = 0.f, a3 = 0.f, dn = 0.f;
    #define P2ACC(qc, i)                      \
      a0 = fmaf(qc, kv[i][0], a0);            \
      a1 = fmaf(qc, kv[i][1], a1);            \
      a2 = fmaf(qc, kv[i][2], a2);            \
      a3 = fmaf(qc, kv[i][3], a3);            \
      dn = fmaf(qc, ks[i], dn);
    P2ACC(q0.x, 0)  P2ACC(q0.y, 1)  P2ACC(q0.z, 2)  P2ACC(q0.w, 3)
    P2ACC(q1.x, 4)  P2ACC(q1.y, 5)  P2ACC(q1.z, 6)  P2ACC(q1.w, 7)
    P2ACC(q2.x, 8)  P2ACC(q2.y, 9)  P2ACC(q2.z, 10) P2ACC(q2.w, 11)
    P2ACC(q3.x, 12) P2ACC(q3.y, 13) P2ACC(q3.z, 14) P2ACC(q3.w, 15)
    #undef P2ACC
    a0 += __shfl_xor(a0, 16, 64); a0 += __shfl_xor(a0, 32, 64);
    a1 += __shfl_xor(a1, 16, 64); a1 += __shfl_xor(a1, 32, 64);
    a2 += __shfl_xor(a2, 16, 64); a2 += __shfl_xor(a2, 32, 64);
    a3 += __shfl_xor(a3, 16, 64); a3 += __shfl_xor(a3, 32, 64);
    dn += __shfl_xor(dn, 16, 64); dn += __shfl_xor(dn, 32, 64);
#if __has_builtin(__builtin_amdgcn_rcpf)
    float z = __builtin_amdgcn_rcpf(dn + EPS_);
#else
    float z = 1.0f / (dn + EPS_);
#endif
    if (dg == (rr & 3)) { o4.x = a0 * z; o4.y = a1 * z; o4.z = a2 * z; o4.w = a3 * z; }
    if ((rr & 3) == 3) {   // full-wave 1 KiB store: lane (dg,eg) -> row base+dg
      const int rb = wave * 16 + (rr & ~3) + dg;
      *(float4*)(ob + (size_t)rb * (H_ * E_) + eg * 4) = o4;
    }
  }
}

extern "C" void kernel_launch(void* const* d_in, const int* in_sizes, int n_in,
                              void* d_out, int out_size, void* d_ws, size_t ws_size,
                              hipStream_t stream) {
  const float* q = (const float*)d_in[0];
  const float* k = (const float*)d_in[1];
  const float* v = (const float*)d_in[2];
  float* outp = (float*)d_out;

  float* kvg = (float*)d_ws;                         // NH * 4096
  float* ksg = kvg + (size_t)NH_ * D_ * E_;          // NH * 64
  float* pkv = ksg + (size_t)NH_ * D_;               // C * NH * 4096
  // pick partial count C by available workspace (prefer 32)
  int C = 32;
  while (C > 1) {
    size_t need = ((size_t)NH_ * D_ * E_ + (size_t)NH_ * D_ +
                   (size_t)C * NH_ * (D_ * E_ + D_)) * sizeof(float);
    if (need <= ws_size) break;
    C >>= 1;
  }
  float* pks = pkv + (size_t)C * NH_ * (D_ * E_);
  const int tiles = S_ / (C * TS_);

  hipLaunchKernelGGL(p1_kv, dim3(C, H_, N_), dim3(512), 0, stream, k, v, pkv, pks, tiles);
  hipLaunchKernelGGL(reduce_kv, dim3(17, NH_), dim3(256), 0, stream, pkv, pks, kvg, ksg, C);
  hipLaunchKernelGGL(p2_out, dim3(L_ / 64, H_, N_), dim3(256), 0, stream, q, kvg, ksg, outp);
}

// Round 6
// 138.443 us; speedup vs baseline: 1.6122x; 1.0466x over previous
//
#include <hip/hip_runtime.h>
#include <cstdint>

#define N_ 4
#define L_ 8192
#define S_ 8192
#define H_ 8
#define D_ 64
#define E_ 64
#define HD_ 512       // H_*D_ row stride in floats
#define NH_ 32        // N_*H_
#define EPS_ 1e-6f
#define RS_ 68        // padded LDS row stride (floats) for K/Q tiles
#define TS_ 32        // s-rows per tile (p1)

__device__ __forceinline__ float elu1(float x) {
  return x > 0.0f ? x + 1.0f : __expf(x);
}

__device__ __forceinline__ void gl_lds_16B(const void* g, void* l) {
  __builtin_amdgcn_global_load_lds(
      (const __attribute__((address_space(1))) unsigned int*)g,
      (__attribute__((address_space(3))) unsigned int*)l, 16, 0, 0);
}

// ---------------- phase 1: partial KV/Ksum per block (NO atomics) -----------
// grid (C, H, N), block 512 (8 waves). Single raw barrier per tile; no vmcnt
// drain in the loop. Pipeline: K prefetched 1 tile ahead (regs), V 2 tiles
// ahead (global_load_lds into 4 rotating buffers), fk ping-pong (2 buffers).
// Issue order per iter: [K(t+1), V(t+2)]; consuming kreg=K(t) at A(t) makes
// the compiler emit a counted vmcnt wait that drains exactly V(t) (older)
// and leaves V(t+1), V(t+2), K(t+1) in flight across the barrier.
// Barrier sits between staging-issue and compute: reaching barrier(t+1)
// implies compute(t) finished for all waves -> buffer rotation race-free.
__global__ __launch_bounds__(512, 6) void p1_kv(const float* __restrict__ keys,
                                                const float* __restrict__ values,
                                                float* __restrict__ pkv,
                                                float* __restrict__ pks,
                                                int tiles) {
  const int chunk = blockIdx.x, h = blockIdx.y, n = blockIdx.z;
  const int tid = threadIdx.x;
  const int w = tid >> 6, lane = tid & 63;
  const int sg = lane >> 4, eg = lane & 15;
  __shared__ float fk_lds[2][TS_ * RS_];    // 17408 B, ping-pong
  __shared__ float v_lds[4][TS_ * 64];      // 32768 B, 4-deep gl_lds dest

  const int srow = tid >> 4;                // 0..31 (also V src row)
  const int scol = (tid & 15) * 4;          // (also V src col)

  const float* Kb = keys   + (size_t)n * S_ * HD_ + h * D_;
  const float* Vb = values + (size_t)n * S_ * HD_ + h * D_;

  float acc[8][4];
  #pragma unroll
  for (int i = 0; i < 8; ++i)
    #pragma unroll
    for (int j = 0; j < 4; ++j) acc[i][j] = 0.0f;
  float4 kss = make_float4(0.f, 0.f, 0.f, 0.f);

  const int dbase = w * 8;
  const int sbase = chunk * tiles * TS_;
  const size_t lanegoff = (size_t)srow * HD_ + scol;

  // prologue — issue order matters: V[0], K[0], V[1]
  gl_lds_16B(Vb + (size_t)sbase * HD_ + lanegoff, &v_lds[0][w * 256]);
  float4 kreg = *(const float4*)(Kb + (size_t)sbase * HD_ + lanegoff);
  gl_lds_16B(Vb + (size_t)(sbase + TS_) * HD_ + lanegoff, &v_lds[1][w * 256]);

  #pragma unroll 1
  for (int t = 0; t < tiles; ++t) {
    // ---- A: stage K tile t from prefetched regs (waits K[t], drains V[t]) --
    {
      float4 f;
      f.x = elu1(kreg.x); f.y = elu1(kreg.y); f.z = elu1(kreg.z); f.w = elu1(kreg.w);
      kss.x += f.x; kss.y += f.y; kss.z += f.z; kss.w += f.w;
      *(float4*)&fk_lds[t & 1][srow * RS_ + scol] = f;
    }
    // ---- B: issue next prefetches (stay in flight across the barrier) -----
    if (t + 1 < tiles)
      kreg = *(const float4*)(Kb + (size_t)(sbase + (t + 1) * TS_) * HD_ + lanegoff);
    if (t + 2 < tiles)
      gl_lds_16B(Vb + (size_t)(sbase + (t + 2) * TS_) * HD_ + lanegoff,
                 &v_lds[(t + 2) & 3][w * 256]);
    // ---- W: own ds_write committed, then raw barrier (NO vmcnt drain) ------
    asm volatile("s_waitcnt lgkmcnt(0)" ::: "memory");
    __builtin_amdgcn_s_barrier();
    __builtin_amdgcn_sched_barrier(0);
    // ---- C: compute tile t ------------------------------------------------
    const float* vb = &v_lds[t & 3][0];
    const float* fb = &fk_lds[t & 1][0];
    #pragma unroll
    for (int g4 = 0; g4 < 8; ++g4) {
      const int s = g4 * 4 + sg;
      float4 vv = *(const float4*)&vb[s * 64 + eg * 4];
      const float* fr = &fb[s * RS_ + dbase];
      float4 k0 = *(const float4*)(fr + 0);
      float4 k1 = *(const float4*)(fr + 4);
      #define ACCROW(di, kc)                          \
        acc[di][0] = fmaf(kc, vv.x, acc[di][0]);      \
        acc[di][1] = fmaf(kc, vv.y, acc[di][1]);      \
        acc[di][2] = fmaf(kc, vv.z, acc[di][2]);      \
        acc[di][3] = fmaf(kc, vv.w, acc[di][3]);
      ACCROW(0, k0.x) ACCROW(1, k0.y) ACCROW(2, k0.z) ACCROW(3, k0.w)
      ACCROW(4, k1.x) ACCROW(5, k1.y) ACCROW(6, k1.z) ACCROW(7, k1.w)
      #undef ACCROW
    }
    // no trailing barrier: next iter's A/B touch the other fk buffer and a
    // V buffer 2 ahead; barrier(t+1) orders everything else.
  }

  // butterfly-reduce the 4-way s split
  #pragma unroll
  for (int i = 0; i < 8; ++i)
    #pragma unroll
    for (int j = 0; j < 4; ++j) {
      float v = acc[i][j];
      v += __shfl_xor(v, 16, 64);
      v += __shfl_xor(v, 32, 64);
      acc[i][j] = v;
    }

  // plain coalesced stores of the block's partial 64x64 tile
  float* pkvb = pkv + ((size_t)chunk * NH_ + (size_t)(n * H_ + h)) * (D_ * E_);
  if (sg == 0) {
    #pragma unroll
    for (int i = 0; i < 8; ++i) {
      float4 o = make_float4(acc[i][0], acc[i][1], acc[i][2], acc[i][3]);
      *(float4*)&pkvb[(dbase + i) * E_ + eg * 4] = o;
    }
  }

  // partial Ksum: block-reduce in LDS. kss goes to v_lds[0] (disjoint from the
  // buffers read in the final compute, tiles%4==0 -> last read buf is 3).
  *(float4*)&v_lds[0][srow * 64 + scol] = kss;
  __syncthreads();
  if (tid < 64) {
    float s = 0.f;
    #pragma unroll
    for (int r = 0; r < 32; ++r) s += v_lds[0][r * 64 + tid];
    pks[((size_t)chunk * NH_ + (size_t)(n * H_ + h)) * D_ + tid] = s;
  }
}

// ---------------- reduce partials -> KV, Ksum ----------------
__global__ __launch_bounds__(256) void reduce_kv(const float* __restrict__ pkv,
                                                 const float* __restrict__ pks,
                                                 float* __restrict__ kvg,
                                                 float* __restrict__ ksg, int C) {
  const int nh = blockIdx.y;
  if (blockIdx.x < 16) {
    const int idx = blockIdx.x * 256 + threadIdx.x;
    float s = 0.f;
    #pragma unroll 1
    for (int c = 0; c < C; ++c)
      s += pkv[((size_t)c * NH_ + nh) * (D_ * E_) + idx];
    kvg[(size_t)nh * (D_ * E_) + idx] = s;
  } else if (threadIdx.x < 64) {
    float s = 0.f;
    #pragma unroll 1
    for (int c = 0; c < C; ++c)
      s += pks[((size_t)c * NH_ + nh) * D_ + threadIdx.x];
    ksg[(size_t)nh * D_ + threadIdx.x] = s;
  }
}

// ---------------- phase 2: out[l][e] = (fQ[l].KV[:,e]) / (fQ[l].Ksum + eps) ---
// grid (L/128, H, N), block 512 (8 waves), wave handles 16 rows (128/block).
// Lane (dg=lane>>4, eg=lane&15). Denominator fused; full-wave float4 stores.
__global__ __launch_bounds__(512, 4) void p2_out(const float* __restrict__ queries,
                                                 const float* __restrict__ kvg,
                                                 const float* __restrict__ ksg,
                                                 float* __restrict__ out) {
  const int lt = blockIdx.x, h = blockIdx.y, n = blockIdx.z;
  const int tid = threadIdx.x;
  const int wave = tid >> 6, lane = tid & 63;
  const int dg = lane >> 4, eg = lane & 15;
  __shared__ float q_lds[128 * RS_];   // 34816 B

  // KV sub-block: kv[di][ej] = KV[16dg+di][4eg+ej]
  const float* kvb = kvg + (size_t)(n * H_ + h) * (D_ * E_);
  float kv[16][4];
  #pragma unroll
  for (int i = 0; i < 16; ++i) {
    float4 t4 = *(const float4*)&kvb[(size_t)(dg * 16 + i) * E_ + eg * 4];
    kv[i][0] = t4.x; kv[i][1] = t4.y; kv[i][2] = t4.z; kv[i][3] = t4.w;
  }
  float ks[16];
  const float* ksb = ksg + (size_t)(n * H_ + h) * D_ + dg * 16;
  #pragma unroll
  for (int i = 0; i < 16; ++i) ks[i] = ksb[i];

  // stage fQ tile [128][64] (elu applied), coalesced float4: 32 rows/pass
  const float* qb = queries + ((size_t)(n * L_ + lt * 128) * H_ + h) * D_;
  {
    const int srow = tid >> 4, scol = (tid & 15) * 4;
    #pragma unroll
    for (int p = 0; p < 4; ++p) {
      const int r = p * 32 + srow;
      float4 q4 = *(const float4*)(qb + (size_t)r * HD_ + scol);
      float4 f;
      f.x = elu1(q4.x); f.y = elu1(q4.y); f.z = elu1(q4.z); f.w = elu1(q4.w);
      *(float4*)&q_lds[r * RS_ + scol] = f;
    }
  }
  __syncthreads();

  float* ob = out + ((size_t)(n * L_ + lt * 128) * H_ + h) * E_;
  float4 o4 = make_float4(0.f, 0.f, 0.f, 0.f);
  #pragma unroll 4
  for (int rr = 0; rr < 16; ++rr) {
    const int r = wave * 16 + rr;
    const float* qr = &q_lds[r * RS_ + dg * 16];
    float4 q0 = *(const float4*)(qr + 0);
    float4 q1 = *(const float4*)(qr + 4);
    float4 q2 = *(const float4*)(qr + 8);
    float4 q3 = *(const float4*)(qr + 12);
    float a0 = 0.f, a1 = 0.f, a2 = 0.f, a3 = 0.f, dn = 0.f;
    #define P2ACC(qc, i)                      \
      a0 = fmaf(qc, kv[i][0], a0);            \
      a1 = fmaf(qc, kv[i][1], a1);            \
      a2 = fmaf(qc, kv[i][2], a2);            \
      a3 = fmaf(qc, kv[i][3], a3);            \
      dn = fmaf(qc, ks[i], dn);
    P2ACC(q0.x, 0)  P2ACC(q0.y, 1)  P2ACC(q0.z, 2)  P2ACC(q0.w, 3)
    P2ACC(q1.x, 4)  P2ACC(q1.y, 5)  P2ACC(q1.z, 6)  P2ACC(q1.w, 7)
    P2ACC(q2.x, 8)  P2ACC(q2.y, 9)  P2ACC(q2.z, 10) P2ACC(q2.w, 11)
    P2ACC(q3.x, 12) P2ACC(q3.y, 13) P2ACC(q3.z, 14) P2ACC(q3.w, 15)
    #undef P2ACC
    a0 += __shfl_xor(a0, 16, 64); a0 += __shfl_xor(a0, 32, 64);
    a1 += __shfl_xor(a1, 16, 64); a1 += __shfl_xor(a1, 32, 64);
    a2 += __shfl_xor(a2, 16, 64); a2 += __shfl_xor(a2, 32, 64);
    a3 += __shfl_xor(a3, 16, 64); a3 += __shfl_xor(a3, 32, 64);
    dn += __shfl_xor(dn, 16, 64); dn += __shfl_xor(dn, 32, 64);
#if __has_builtin(__builtin_amdgcn_rcpf)
    float z = __builtin_amdgcn_rcpf(dn + EPS_);
#else
    float z = 1.0f / (dn + EPS_);
#endif
    if (dg == (rr & 3)) { o4.x = a0 * z; o4.y = a1 * z; o4.z = a2 * z; o4.w = a3 * z; }
    if ((rr & 3) == 3) {   // full-wave 1 KiB store: lane (dg,eg) -> row base+dg
      const int rb = wave * 16 + (rr & ~3) + dg;
      *(float4*)(ob + (size_t)rb * (H_ * E_) + eg * 4) = o4;
    }
  }
}

extern "C" void kernel_launch(void* const* d_in, const int* in_sizes, int n_in,
                              void* d_out, int out_size, void* d_ws, size_t ws_size,
                              hipStream_t stream) {
  const float* q = (const float*)d_in[0];
  const float* k = (const float*)d_in[1];
  const float* v = (const float*)d_in[2];
  float* outp = (float*)d_out;

  float* kvg = (float*)d_ws;                         // NH * 4096
  float* ksg = kvg + (size_t)NH_ * D_ * E_;          // NH * 64
  float* pkv = ksg + (size_t)NH_ * D_;               // C * NH * 4096
  int C = 32;
  while (C > 1) {
    size_t need = ((size_t)NH_ * D_ * E_ + (size_t)NH_ * D_ +
                   (size_t)C * NH_ * (D_ * E_ + D_)) * sizeof(float);
    if (need <= ws_size) break;
    C >>= 1;
  }
  float* pks = pkv + (size_t)C * NH_ * (D_ * E_);
  const int tiles = S_ / (C * TS_);

  hipLaunchKernelGGL(p1_kv, dim3(C, H_, N_), dim3(512), 0, stream, k, v, pkv, pks, tiles);
  hipLaunchKernelGGL(reduce_kv, dim3(17, NH_), dim3(256), 0, stream, pkv, pks, kvg, ksg, C);
  hipLaunchKernelGGL(p2_out, dim3(L_ / 128, H_, N_), dim3(512), 0, stream, q, kvg, ksg, outp);
}

// Round 7
// 134.099 us; speedup vs baseline: 1.6644x; 1.0324x over previous
//
#include <hip/hip_runtime.h>
#include <cstdint>

#define N_ 4
#define L_ 8192
#define S_ 8192
#define H_ 8
#define D_ 64
#define E_ 64
#define HD_ 512       // H_*D_ row stride in floats
#define NH_ 32        // N_*H_
#define EPS_ 1e-6f
#define RS_ 68        // padded LDS row stride (floats) for p2 Q tile
#define TS_ 32        // s-rows per tile (p1)

__device__ __forceinline__ float elu1(float x) {
  return x > 0.0f ? x + 1.0f : __expf(x);
}

__device__ __forceinline__ void gl_lds_16B(const void* g, void* l) {
  __builtin_amdgcn_global_load_lds(
      (const __attribute__((address_space(1))) unsigned int*)g,
      (__attribute__((address_space(3))) unsigned int*)l, 16, 0, 0);
}

// ---------------- phase 1: partial KV/Ksum per block (NO atomics) -----------
// grid (C=32, H, N) = 1024 blocks, block 512 (8 waves).
// LDS = 16384 (fk ping-pong, unpadded+XOR-swizzled) + 24576 (V 3-deep) = 40960
// = exactly 163840/4 -> 4 blocks/CU, grid = one clean dispatch round, 32 w/CU.
// Pipeline (single barrier/tile, counted vmcnt, never drain-0 in loop):
//   A: elu+stage K(t) from prefetched regs    (kreg wait drains old loads)
//   B: issue V(t+1) [gl_lds, buf (t+1)%3] and K(t+1) [regs]
//   W: lgkmcnt(0); s_barrier; vmcnt(2)  <- V(t) guaranteed landed; V(t+1),
//      K(t+1) stay in flight across the barrier; sched_barrier pins C below.
//   C: compute tile t.
// 3-deep V is the min race-free depth at 1-ahead (barrier skew <= 1 iter:
// writer B(t+1) hits buf[(t+2)%3]; readers C(t)/C(t+1) hit t%3,(t+1)%3).
// fk swizzle: store col^((srow&3)<<3), read base (8w)^(sg<<3): loop-invariant
// per lane, 16B-aligned, spreads the 4 sg broadcast-reads over banks 0/8/16/24.
__global__ __launch_bounds__(512, 8) void p1_kv(const float* __restrict__ keys,
                                                const float* __restrict__ values,
                                                float* __restrict__ pkv,
                                                float* __restrict__ pks,
                                                int tiles) {
  const int chunk = blockIdx.x, h = blockIdx.y, n = blockIdx.z;
  const int tid = threadIdx.x;
  const int w = tid >> 6, lane = tid & 63;
  const int sg = lane >> 4, eg = lane & 15;
  __shared__ float fk_lds[2][TS_ * 64];     // 16384 B, ping-pong, swizzled
  __shared__ float v_lds[3][TS_ * 64];      // 24576 B, 3-deep gl_lds dest

  const int srow = tid >> 4;                // 0..31 (also V src row)
  const int scol = (tid & 15) * 4;          // (also V src col)
  const int scolw = scol ^ ((srow & 3) << 3);   // swizzled fk write col
  const int dswz  = (w * 8) ^ (sg << 3);        // swizzled fk read base

  const float* Kb = keys   + (size_t)n * S_ * HD_ + h * D_;
  const float* Vb = values + (size_t)n * S_ * HD_ + h * D_;

  float acc[8][4];
  #pragma unroll
  for (int i = 0; i < 8; ++i)
    #pragma unroll
    for (int j = 0; j < 4; ++j) acc[i][j] = 0.0f;
  float4 kss = make_float4(0.f, 0.f, 0.f, 0.f);

  const int sbase = chunk * tiles * TS_;
  const size_t lanegoff = (size_t)srow * HD_ + scol;

  // prologue: V(0) -> buf0, K(0) -> regs
  gl_lds_16B(Vb + (size_t)sbase * HD_ + lanegoff, &v_lds[0][w * 256]);
  float4 kreg = *(const float4*)(Kb + (size_t)sbase * HD_ + lanegoff);

  int vr = 0, vw = 1;   // V read/write buffer indices (mod 3)
  #pragma unroll 1
  for (int t = 0; t < tiles; ++t) {
    // ---- A: stage K tile t (consuming kreg forces wait on K(t)) -----------
    {
      float4 f;
      f.x = elu1(kreg.x); f.y = elu1(kreg.y); f.z = elu1(kreg.z); f.w = elu1(kreg.w);
      kss.x += f.x; kss.y += f.y; kss.z += f.z; kss.w += f.w;
      *(float4*)&fk_lds[t & 1][srow * 64 + scolw] = f;
    }
    // ---- B: issue next prefetches (stay in flight across the barrier) -----
    if (t + 1 < tiles) {
      gl_lds_16B(Vb + (size_t)(sbase + (t + 1) * TS_) * HD_ + lanegoff,
                 &v_lds[vw][w * 256]);
      kreg = *(const float4*)(Kb + (size_t)(sbase + (t + 1) * TS_) * HD_ + lanegoff);
    }
    // ---- W: own ds_write committed; barrier; counted vmcnt ----------------
    asm volatile("s_waitcnt lgkmcnt(0)" ::: "memory");
    __builtin_amdgcn_s_barrier();
    asm volatile("s_waitcnt vmcnt(2)" ::: "memory");  // V(t) landed; 2 newest stay
    __builtin_amdgcn_sched_barrier(0);
    // ---- C: compute tile t -------------------------------------------------
    const float* vb = &v_lds[vr][0];
    const float* fb = &fk_lds[t & 1][0];
    #pragma unroll
    for (int g4 = 0; g4 < 8; ++g4) {
      const int s = g4 * 4 + sg;
      float4 vv = *(const float4*)&vb[s * 64 + eg * 4];
      const float* fr = &fb[s * 64 + dswz];
      float4 k0 = *(const float4*)(fr + 0);
      float4 k1 = *(const float4*)(fr + 4);
      #define ACCROW(di, kc)                          \
        acc[di][0] = fmaf(kc, vv.x, acc[di][0]);      \
        acc[di][1] = fmaf(kc, vv.y, acc[di][1]);      \
        acc[di][2] = fmaf(kc, vv.z, acc[di][2]);      \
        acc[di][3] = fmaf(kc, vv.w, acc[di][3]);
      ACCROW(0, k0.x) ACCROW(1, k0.y) ACCROW(2, k0.z) ACCROW(3, k0.w)
      ACCROW(4, k1.x) ACCROW(5, k1.y) ACCROW(6, k1.z) ACCROW(7, k1.w)
      #undef ACCROW
    }
    vr = (vr == 2) ? 0 : vr + 1;
    vw = (vw == 2) ? 0 : vw + 1;
  }

  // butterfly-reduce the 4-way s split
  #pragma unroll
  for (int i = 0; i < 8; ++i)
    #pragma unroll
    for (int j = 0; j < 4; ++j) {
      float v = acc[i][j];
      v += __shfl_xor(v, 16, 64);
      v += __shfl_xor(v, 32, 64);
      acc[i][j] = v;
    }

  // plain coalesced stores of the block's partial 64x64 tile
  float* pkvb = pkv + ((size_t)chunk * NH_ + (size_t)(n * H_ + h)) * (D_ * E_);
  if (sg == 0) {
    #pragma unroll
    for (int i = 0; i < 8; ++i) {
      float4 o = make_float4(acc[i][0], acc[i][1], acc[i][2], acc[i][3]);
      *(float4*)&pkvb[(w * 8 + i) * E_ + eg * 4] = o;
    }
  }

  // partial Ksum: block-reduce in fk_lds[0] (all fk reads long done; last
  // compute used fk_lds[(tiles-1)&1] and a barrier below orders the reuse)
  __syncthreads();
  *(float4*)&fk_lds[0][srow * 64 + scol] = kss;
  __syncthreads();
  if (tid < 64) {
    float s = 0.f;
    #pragma unroll
    for (int r = 0; r < 32; ++r) s += fk_lds[0][r * 64 + tid];
    pks[((size_t)chunk * NH_ + (size_t)(n * H_ + h)) * D_ + tid] = s;
  }
}

// ---------------- reduce partials -> KV, Ksum ----------------
__global__ __launch_bounds__(256) void reduce_kv(const float* __restrict__ pkv,
                                                 const float* __restrict__ pks,
                                                 float* __restrict__ kvg,
                                                 float* __restrict__ ksg, int C) {
  const int nh = blockIdx.y;
  if (blockIdx.x < 16) {
    const int idx = blockIdx.x * 256 + threadIdx.x;
    float s = 0.f;
    #pragma unroll 1
    for (int c = 0; c < C; ++c)
      s += pkv[((size_t)c * NH_ + nh) * (D_ * E_) + idx];
    kvg[(size_t)nh * (D_ * E_) + idx] = s;
  } else if (threadIdx.x < 64) {
    float s = 0.f;
    #pragma unroll 1
    for (int c = 0; c < C; ++c)
      s += pks[((size_t)c * NH_ + nh) * D_ + threadIdx.x];
    ksg[(size_t)nh * D_ + threadIdx.x] = s;
  }
}

// ---------------- phase 2: out[l][e] = (fQ[l].KV[:,e]) / (fQ[l].Ksum + eps) ---
// grid (L/128, H, N), block 512 (8 waves), wave handles 16 rows (128/block).
// Lane (dg=lane>>4, eg=lane&15). Denominator fused; full-wave float4 stores.
__global__ __launch_bounds__(512, 4) void p2_out(const float* __restrict__ queries,
                                                 const float* __restrict__ kvg,
                                                 const float* __restrict__ ksg,
                                                 float* __restrict__ out) {
  const int lt = blockIdx.x, h = blockIdx.y, n = blockIdx.z;
  const int tid = threadIdx.x;
  const int wave = tid >> 6, lane = tid & 63;
  const int dg = lane >> 4, eg = lane & 15;
  __shared__ float q_lds[128 * RS_];   // 34816 B

  // KV sub-block: kv[di][ej] = KV[16dg+di][4eg+ej]
  const float* kvb = kvg + (size_t)(n * H_ + h) * (D_ * E_);
  float kv[16][4];
  #pragma unroll
  for (int i = 0; i < 16; ++i) {
    float4 t4 = *(const float4*)&kvb[(size_t)(dg * 16 + i) * E_ + eg * 4];
    kv[i][0] = t4.x; kv[i][1] = t4.y; kv[i][2] = t4.z; kv[i][3] = t4.w;
  }
  float ks[16];
  const float* ksb = ksg + (size_t)(n * H_ + h) * D_ + dg * 16;
  #pragma unroll
  for (int i = 0; i < 16; ++i) ks[i] = ksb[i];

  // stage fQ tile [128][64] (elu applied), coalesced float4: 32 rows/pass
  const float* qb = queries + ((size_t)(n * L_ + lt * 128) * H_ + h) * D_;
  {
    const int srow = tid >> 4, scol = (tid & 15) * 4;
    #pragma unroll
    for (int p = 0; p < 4; ++p) {
      const int r = p * 32 + srow;
      float4 q4 = *(const float4*)(qb + (size_t)r * HD_ + scol);
      float4 f;
      f.x = elu1(q4.x); f.y = elu1(q4.y); f.z = elu1(q4.z); f.w = elu1(q4.w);
      *(float4*)&q_lds[r * RS_ + scol] = f;
    }
  }
  __syncthreads();

  float* ob = out + ((size_t)(n * L_ + lt * 128) * H_ + h) * E_;
  float4 o4 = make_float4(0.f, 0.f, 0.f, 0.f);
  #pragma unroll 4
  for (int rr = 0; rr < 16; ++rr) {
    const int r = wave * 16 + rr;
    const float* qr = &q_lds[r * RS_ + dg * 16];
    float4 q0 = *(const float4*)(qr + 0);
    float4 q1 = *(const float4*)(qr + 4);
    float4 q2 = *(const float4*)(qr + 8);
    float4 q3 = *(const float4*)(qr + 12);
    float a0 = 0.f, a1 = 0.f, a2 = 0.f, a3 = 0.f, dn = 0.f;
    #define P2ACC(qc, i)                      \
      a0 = fmaf(qc, kv[i][0], a0);            \
      a1 = fmaf(qc, kv[i][1], a1);            \
      a2 = fmaf(qc, kv[i][2], a2);            \
      a3 = fmaf(qc, kv[i][3], a3);            \
      dn = fmaf(qc, ks[i], dn);
    P2ACC(q0.x, 0)  P2ACC(q0.y, 1)  P2ACC(q0.z, 2)  P2ACC(q0.w, 3)
    P2ACC(q1.x, 4)  P2ACC(q1.y, 5)  P2ACC(q1.z, 6)  P2ACC(q1.w, 7)
    P2ACC(q2.x, 8)  P2ACC(q2.y, 9)  P2ACC(q2.z, 10) P2ACC(q2.w, 11)
    P2ACC(q3.x, 12) P2ACC(q3.y, 13) P2ACC(q3.z, 14) P2ACC(q3.w, 15)
    #undef P2ACC
    a0 += __shfl_xor(a0, 16, 64); a0 += __shfl_xor(a0, 32, 64);
    a1 += __shfl_xor(a1, 16, 64); a1 += __shfl_xor(a1, 32, 64);
    a2 += __shfl_xor(a2, 16, 64); a2 += __shfl_xor(a2, 32, 64);
    a3 += __shfl_xor(a3, 16, 64); a3 += __shfl_xor(a3, 32, 64);
    dn += __shfl_xor(dn, 16, 64); dn += __shfl_xor(dn, 32, 64);
#if __has_builtin(__builtin_amdgcn_rcpf)
    float z = __builtin_amdgcn_rcpf(dn + EPS_);
#else
    float z = 1.0f / (dn + EPS_);
#endif
    if (dg == (rr & 3)) { o4.x = a0 * z; o4.y = a1 * z; o4.z = a2 * z; o4.w = a3 * z; }
    if ((rr & 3) == 3) {   // full-wave 1 KiB store: lane (dg,eg) -> row base+dg
      const int rb = wave * 16 + (rr & ~3) + dg;
      *(float4*)(ob + (size_t)rb * (H_ * E_) + eg * 4) = o4;
    }
  }
}

extern "C" void kernel_launch(void* const* d_in, const int* in_sizes, int n_in,
                              void* d_out, int out_size, void* d_ws, size_t ws_size,
                              hipStream_t stream) {
  const float* q = (const float*)d_in[0];
  const float* k = (const float*)d_in[1];
  const float* v = (const float*)d_in[2];
  float* outp = (float*)d_out;

  float* kvg = (float*)d_ws;                         // NH * 4096
  float* ksg = kvg + (size_t)NH_ * D_ * E_;          // NH * 64
  float* pkv = ksg + (size_t)NH_ * D_;               // C * NH * 4096
  int C = 32;
  while (C > 1) {
    size_t need = ((size_t)NH_ * D_ * E_ + (size_t)NH_ * D_ +
                   (size_t)C * NH_ * (D_ * E_ + D_)) * sizeof(float);
    if (need <= ws_size) break;
    C >>= 1;
  }
  float* pks = pkv + (size_t)C * NH_ * (D_ * E_);
  const int tiles = S_ / (C * TS_);

  hipLaunchKernelGGL(p1_kv, dim3(C, H_, N_), dim3(512), 0, stream, k, v, pkv, pks, tiles);
  hipLaunchKernelGGL(reduce_kv, dim3(17, NH_), dim3(256), 0, stream, pkv, pks, kvg, ksg, C);
  hipLaunchKernelGGL(p2_out, dim3(L_ / 128, H_, N_), dim3(512), 0, stream, q, kvg, ksg, outp);
}